// Round 8
// baseline (1115.299 us; speedup 1.0000x reference)
//
#include <hip/hip_runtime.h>
#include <hip/hip_bf16.h>
#include <math.h>

typedef _Float16 f16;
typedef _Float16 half8 __attribute__((ext_vector_type(8)));
typedef float f32x4 __attribute__((ext_vector_type(4)));

#define IMG 128
#define CIN 96
#define CH  192
#define SCALE_Q 0.2041241452319315f   // 24^-0.5

__device__ __forceinline__ f32x4 mfma16(half8 a, half8 b, f32x4 c) {
  return __builtin_amdgcn_mfma_f32_16x16x32_f16(a, b, c, 0, 0, 0);
}

// weight fragment loader: WH=true -> pre-converted f16 row-major [N][K];
// WH=false -> fp32 row-major with per-element RTE cvt (bit-exact legacy path)
template <bool WH>
__device__ __forceinline__ half8 loadW(const void* W, int row, int k, int ldk) {
  if constexpr (WH) {
    return *(const half8*)((const f16*)W + (size_t)row * ldk + k);
  } else {
    const float* p = (const float*)W + (size_t)row * ldk + k;
    const float4 a = *(const float4*)p;
    const float4 b = *(const float4*)(p + 4);
    half8 h;
    h[0] = (f16)a.x; h[1] = (f16)a.y; h[2] = (f16)a.z; h[3] = (f16)a.w;
    h[4] = (f16)b.x; h[5] = (f16)b.y; h[6] = (f16)b.z; h[7] = (f16)b.w;
    return h;
  }
}

// exact-GELU via Abramowitz-Stegun erf approx (|err| <= 1.5e-7)
// rcp via v_rcp_f32 (~1 ulp) instead of full div: error far below f16 noise
__device__ __forceinline__ float gelu(float x) {
  const float u = 0.70710678118654752f * x;
  const float a = fabsf(u);
  const float t = __builtin_amdgcn_rcpf(1.0f + 0.3275911f * a);
  const float poly = t * (0.254829592f + t * (-0.284496736f +
                     t * (1.421413741f + t * (-1.453152027f + t * 1.061405429f))));
  float er = 1.0f - poly * __expf(-u * u);
  er = (u < 0.f) ? -er : er;
  return 0.5f * x * (1.0f + er);
}

// ---------- kernel 0: conv weights OIHW fp32 -> [co][(ky*3+kx)*96+ci] f16;
//                      optionally qW/kvW fp32 -> f16 straight copy into wq16 ----------
__global__ __launch_bounds__(256) void reorder_w(
    const float* __restrict__ pq_w, const float* __restrict__ pv_w,
    const float* __restrict__ qW, const float* __restrict__ kvW,
    f16* __restrict__ Wr, f16* __restrict__ wq16) {
  const int i = blockIdx.x * 256 + threadIdx.x;
  if (i < 2 * 192 * 864) {
    const int which = i / (192 * 864);
    const int rem = i - which * (192 * 864);
    const int co = rem / 864;
    const int kk = rem - co * 864;
    const int s = kk / 96;           // ky*3+kx
    const int ci = kk - s * 96;
    const float* src = which ? pv_w : pq_w;
    Wr[i] = (f16)src[co * 864 + ci * 9 + s];
  } else if (wq16) {
    const int j = i - 2 * 192 * 864;       // 0..110591: qW(36864) then kvW(73728)
    if (j < 110592)
      wq16[j] = (f16)(j < 36864 ? qW[j] : kvW[j - 36864]);
  }
}

// ---------- kernel 0b (after attn64): apW,w1,w2 fp32 -> f16 into dead v buffer ----------
__global__ __launch_bounds__(256) void reorder_w2(
    const float* __restrict__ apW, const float* __restrict__ w1,
    const float* __restrict__ w2, f16* __restrict__ dst) {
  const int i = blockIdx.x * 256 + threadIdx.x;
  if (i >= 331776) return;                 // 36864 + 147456 + 147456
  float v;
  if (i < 36864)       v = apW[i];
  else if (i < 184320) v = w1[i - 36864];
  else                 v = w2[i - 184320];
  dst[i] = (f16)v;
}

// ---------- kernel 1: implicit-GEMM MFMA 3x3 conv, 2 output rows per block ----------
// grid 2048 = {which(2)} x {b(8)} x {ypair(64)} x {xseg(2)}; block 256 (4 waves)
// M = 128 pixels (2 rows x 64), N = 192, K = 9*96   [round-5 proven form]
__global__ __launch_bounds__(256, 2) void conv3x3_mfma(
    const float* __restrict__ xin, const float* __restrict__ vin,
    const f16* __restrict__ Wr,
    const float* __restrict__ pq_b, const float* __restrict__ pv_b,
    f16* __restrict__ xp, f16* __restrict__ vp) {
  int bz = blockIdx.x;
  const int which = bz >> 10; bz &= 1023;
  const int b = bz >> 7;
  const int yp = (bz >> 1) & 63;
  const int xseg = bz & 1;
  const int y0 = yp * 2;
  const int x0 = xseg * 64;
  const float* in = which ? vin : xin;
  const float* bias = which ? pv_b : pq_b;
  const f16* W = Wr + (size_t)which * 192 * 864;
  f16* out = which ? vp : xp;

  // im2col halo tile: [r(4)][x(66)][c(96)], pixel stride 104
  // reused after MFMA as output staging [tok(128)][ch(192)] stride 204
  __shared__ __align__(16) f16 ST[4 * 66 * 104];
  const int tid = threadIdx.x;
  // batched branchless staging: 99 elements/thread = 9 batches x 11
  #pragma unroll
  for (int batch = 0; batch < 9; ++batch) {
    float vals[11];
    bool oks[11];
    int sts[11];
    #pragma unroll
    for (int u = 0; u < 11; ++u) {
      const int i = tid + (batch * 11 + u) * 256;
      const int r = i / 6336;                 // 6336 = 96*66
      const int rem2 = i - r * 6336;
      const int c = rem2 / 66;
      const int xx = rem2 - c * 66;
      const int gy = y0 + r - 1;
      const int gx = x0 - 1 + xx;
      oks[u] = ((unsigned)gy < IMG) && ((unsigned)gx < IMG);
      const int cgy = min(max(gy, 0), IMG - 1);
      const int cgx = min(max(gx, 0), IMG - 1);
      vals[u] = in[(((size_t)b * CIN + c) * IMG + cgy) * IMG + cgx];
      sts[u] = (r * 66 + xx) * 104 + c;
    }
    #pragma unroll
    for (int u = 0; u < 11; ++u)
      ST[sts[u]] = oks[u] ? (f16)vals[u] : (f16)0.f;
  }
  __syncthreads();

  const int lane = tid & 63;
  const int wv = tid >> 6;
  const int l15 = lane & 15;
  const int quad = lane >> 4;
  const int nb = wv * 48;          // N-slice 48 per wave

  f32x4 acc[8][3];
  #pragma unroll
  for (int mt = 0; mt < 8; ++mt)
    #pragma unroll
    for (int j = 0; j < 3; ++j) acc[mt][j] = (f32x4)0.f;

  #pragma unroll
  for (int s = 0; s < 9; ++s) {
    const int ky = s / 3, kx = s - ky * 3;
    #pragma unroll
    for (int kstep = 0; kstep < 3; ++kstep) {
      const int k = kstep * 32 + quad * 8;   // ci offset
      half8 a[8];
      #pragma unroll
      for (int mt = 0; mt < 8; ++mt)
        a[mt] = *(const half8*)(ST + (((mt >> 2) + ky) * 66 + (mt & 3) * 16 + l15 + kx) * 104 + k);
      #pragma unroll
      for (int j = 0; j < 3; ++j) {
        const half8 bf = *(const half8*)(W + (size_t)(nb + j * 16 + l15) * 864 + s * 96 + k);
        #pragma unroll
        for (int mt = 0; mt < 8; ++mt) acc[mt][j] = mfma16(a[mt], bf, acc[mt][j]);
      }
    }
  }
  __syncthreads();   // all ST reads done; reuse as output staging

  // transpose through LDS: [lt(128)][ch(192)] stride 204
  #pragma unroll
  for (int j = 0; j < 3; ++j) {
    const int n = nb + j * 16 + l15;
    const float bn = bias[n];
    #pragma unroll
    for (int mt = 0; mt < 8; ++mt) {
      const int lt = (mt >> 2) * 64 + (mt & 3) * 16 + quad * 4;
      #pragma unroll
      for (int reg = 0; reg < 4; ++reg)
        ST[(lt + reg) * 204 + n] = (f16)(acc[mt][j][reg] + bn);
    }
  }
  __syncthreads();

  // contiguous half8 stores: 128 tok x 24 chunks = 3072 / 256 threads = 12 each
  const size_t rowbase0 = ((size_t)(b * IMG + y0) * IMG + x0) * CH;
  const size_t rowbase1 = ((size_t)(b * IMG + y0 + 1) * IMG + x0) * CH;
  #pragma unroll
  for (int it = 0; it < 12; ++it) {
    const int i = tid + it * 256;
    const int tok = i / 24, c8 = i - tok * 24;
    const half8 hval = *(const half8*)(ST + tok * 204 + c8 * 8);
    const int trow = tok >> 6, tx = tok & 63;
    f16* dst = out + (trow ? rowbase1 : rowbase0) + (size_t)tx * CH + c8 * 8;
    *(half8*)dst = hval;
  }
}

// ---------- kernel 2: LN1/LN2 + q/k/v projection (MFMA) + res=x+v in-place ----------
// block 256 (4 waves), Mtile = 32 tokens, N = 576 (q|k|v), K = 192
template <bool WH>
__global__ __launch_bounds__(256, 1) void ln_qkv_mfma(
    f16* __restrict__ xp, const f16* __restrict__ vp,
    const float* __restrict__ n1w, const float* __restrict__ n1b,
    const float* __restrict__ n2w, const float* __restrict__ n2b,
    const void* __restrict__ qW, const void* __restrict__ kvW,
    f16* __restrict__ qb, f16* __restrict__ kb, f16* __restrict__ vb) {
  const int tid = threadIdx.x;
  const int lane = tid & 63;
  const int wv = tid >> 6;
  const int l15 = lane & 15;
  const int quad = lane >> 4;
  const int tok0 = blockIdx.x * 32;
  // union: Ax (stride 200, 6400) + Av (6400) during MFMA; Os (32x588) after
  __shared__ __align__(16) f16 U[32 * 588];
  f16* Ax = U;
  f16* Av = U + 6400;

  { // stage + LN (8 threads per token, 24 elements each)
    const int r = tid >> 3;
    const int s = tid & 7;
    const size_t gbase = (size_t)(tok0 + r) * 192 + s * 24;
    half8 hx[3], hv[3];
    const half8* px = (const half8*)(xp + gbase);
    const half8* pv = (const half8*)(vp + gbase);
    #pragma unroll
    for (int i = 0; i < 3; ++i) { hx[i] = px[i]; hv[i] = pv[i]; }
    float xv[24], vvv[24];
    float sx = 0.f, sx2 = 0.f, sv = 0.f, sv2 = 0.f;
    #pragma unroll
    for (int i = 0; i < 24; ++i) {
      xv[i] = (float)hx[i >> 3][i & 7];
      vvv[i] = (float)hv[i >> 3][i & 7];
      sx += xv[i]; sx2 += xv[i] * xv[i];
      sv += vvv[i]; sv2 += vvv[i] * vvv[i];
    }
    half8 hr[3];
    #pragma unroll
    for (int i = 0; i < 24; ++i) hr[i >> 3][i & 7] = (f16)(xv[i] + vvv[i]);
    half8* pr = (half8*)(xp + gbase);
    #pragma unroll
    for (int i = 0; i < 3; ++i) pr[i] = hr[i];   // residual, in-place
    #pragma unroll
    for (int m = 1; m < 8; m <<= 1) {
      sx += __shfl_xor(sx, m, 64); sx2 += __shfl_xor(sx2, m, 64);
      sv += __shfl_xor(sv, m, 64); sv2 += __shfl_xor(sv2, m, 64);
    }
    const float mx = sx * (1.f / 192.f);
    const float rx = rsqrtf(sx2 * (1.f / 192.f) - mx * mx + 1e-5f);
    const float mv = sv * (1.f / 192.f);
    const float rv = rsqrtf(sv2 * (1.f / 192.f) - mv * mv + 1e-5f);
    #pragma unroll
    for (int i = 0; i < 24; ++i) {
      const int c = s * 24 + i;
      Ax[r * 200 + c] = (f16)((xv[i] - mx) * rx * n1w[c] + n1b[c]);
      Av[r * 200 + c] = (f16)((vvv[i] - mv) * rv * n2w[c] + n2b[c]);
    }
  }
  __syncthreads();

  const int nb = wv * 144;
  f32x4 acc[2][9];
  #pragma unroll
  for (int mt = 0; mt < 2; ++mt)
    #pragma unroll
    for (int j = 0; j < 9; ++j) acc[mt][j] = (f32x4)0.f;

  for (int kc = 0; kc < 6; ++kc) {
    const int k = kc * 32 + quad * 8;
    half8 wb[9];
    #pragma unroll
    for (int j = 0; j < 9; ++j) {
      const int n0 = nb + j * 16;
      if (n0 < 192) wb[j] = loadW<WH>(qW, n0 + l15, k, 192);
      else          wb[j] = loadW<WH>(kvW, n0 - 192 + l15, k, 192);
    }
    const half8 ax0 = *(const half8*)(Ax + l15 * 200 + k);
    const half8 ax1 = *(const half8*)(Ax + (16 + l15) * 200 + k);
    const half8 av0 = *(const half8*)(Av + l15 * 200 + k);
    const half8 av1 = *(const half8*)(Av + (16 + l15) * 200 + k);
    #pragma unroll
    for (int j = 0; j < 9; ++j) {
      const int n0 = nb + j * 16;
      if (n0 < 192) {
        acc[0][j] = mfma16(ax0, wb[j], acc[0][j]);
        acc[1][j] = mfma16(ax1, wb[j], acc[1][j]);
      } else {
        acc[0][j] = mfma16(av0, wb[j], acc[0][j]);
        acc[1][j] = mfma16(av1, wb[j], acc[1][j]);
      }
    }
  }
  __syncthreads();   // Ax/Av reads done; reuse U as output staging

  // stage acc into Os[r(32)][n(576)] stride 588 (f16 conversion identical to before)
  #pragma unroll
  for (int j = 0; j < 9; ++j) {
    const int n = nb + j * 16 + l15;
    const float scale = (n < 192) ? SCALE_Q : 1.f;
    #pragma unroll
    for (int mt = 0; mt < 2; ++mt)
      #pragma unroll
      for (int reg = 0; reg < 4; ++reg) {
        const int r = mt * 16 + quad * 4 + reg;
        U[r * 588 + n] = (f16)(acc[mt][j][reg] * scale);
      }
  }
  __syncthreads();

  // copy out: 3 bufs x 4 windows x 8 heads x (8 tok x 3 chunks) = 2304 half8
  // all 32 tokens share one image row y; x = x0b + r
  const int yrow = (tok0 >> 7) & 127;
  const int bb = tok0 >> 14;
  const int x0b = tok0 & 127;
  const int wib = bb * 256 + ((yrow >> 3) << 4) + (x0b >> 3);  // window of r=0
  const int trow = (yrow & 7) * 8;
  f16* const bufs[3] = {qb, kb, vb};
  #pragma unroll
  for (int it = 0; it < 9; ++it) {
    const int i = tid + it * 256;
    const int c24 = i % 24;            // t8*3 + c3
    const int g = i / 24;              // buf*32 + wloc*8 + h
    const int h = g & 7;
    const int g2 = g >> 3;             // buf*4 + wloc
    const int wloc = g2 & 3;
    const int buf = g2 >> 2;
    const int t8 = c24 / 3, c3 = c24 - t8 * 3;
    const int r = wloc * 8 + t8;
    const half8 hval = *(const half8*)(U + r * 588 + buf * 192 + h * 24 + c3 * 8);
    f16* dst = bufs[buf] + (size_t)(wib + wloc) * 12288 + (trow + t8) * 24 + h * 1536 + c3 * 8;
    *(half8*)dst = hval;
  }
}

// ---------- kernel 3: windowed attention, one block (1 wave) per (window, head) ----------
__global__ __launch_bounds__(64) void attn64(
    const f16* __restrict__ qb, const f16* __restrict__ kb,
    const f16* __restrict__ vb, const float* __restrict__ rpb,
    f16* __restrict__ fb) {
  const int wh = blockIdx.x;           // w*8 + h
  const int h = wh & 7;
  const int w = wh >> 3;
  const int t = threadIdx.x;
  __shared__ __align__(16) float ks[64 * 24];
  __shared__ __align__(16) float vs[64 * 24];
  __shared__ float bsh[225];
  const f16* kbase = kb + (size_t)wh * 1536;
  const f16* vbase = vb + (size_t)wh * 1536;
  // vectorized half8 loads: 192 chunks / 64 threads = 3 each
  #pragma unroll
  for (int it = 0; it < 3; ++it) {
    const int i = t + it * 64;
    const half8 hk = *(const half8*)(kbase + (size_t)i * 8);
    const half8 hv = *(const half8*)(vbase + (size_t)i * 8);
    #pragma unroll
    for (int e = 0; e < 8; ++e) {
      ks[i * 8 + e] = (float)hk[e];
      vs[i * 8 + e] = (float)hv[e];
    }
  }
  for (int i = t; i < 225; i += 64) bsh[i] = rpb[i * 8 + h];
  float q[24];
  {
    const half8* qrow = (const half8*)(qb + ((size_t)wh * 64 + t) * 24);
    half8 hq[3];
    #pragma unroll
    for (int i = 0; i < 3; ++i) hq[i] = qrow[i];
    #pragma unroll
    for (int d = 0; d < 24; ++d) q[d] = (float)hq[d >> 3][d & 7];
  }
  __syncthreads();
  const int qy = t >> 3, qx = t & 7;
  float s[64];
  float mx = -1e30f;
  #pragma unroll
  for (int kk = 0; kk < 64; ++kk) {
    float acc = 0.f;
    #pragma unroll
    for (int d = 0; d < 24; ++d) acc += q[d] * ks[kk * 24 + d];
    const int ky = kk >> 3, kx = kk & 7;
    acc += bsh[(qy - ky + 7) * 15 + (qx - kx + 7)];
    s[kk] = acc;
    mx = fmaxf(mx, acc);
  }
  float sum = 0.f;
  #pragma unroll
  for (int kk = 0; kk < 64; ++kk) { const float e = __expf(s[kk] - mx); s[kk] = e; sum += e; }
  const float inv = 1.0f / sum;
  float o[24];
  #pragma unroll
  for (int d = 0; d < 24; ++d) o[d] = 0.f;
  #pragma unroll
  for (int kk = 0; kk < 64; ++kk) {
    const float p = s[kk];
    #pragma unroll
    for (int d = 0; d < 24; ++d) o[d] += p * vs[kk * 24 + d];
  }
  f16* orow = fb + ((size_t)w * 64 + t) * 192 + h * 24;
  #pragma unroll
  for (int d = 0; d < 24; ++d) orow[d] = (f16)(o[d] * inv);
}

// ---------- kernel 4: attn-proj + LN3 + fc1 + GELU + fc2 + x2 + LN4 + residual + NCHW ----------
// M=64 (one full window) per block, 512 threads (8 waves), grid 2048.
// Phase A/fc2/LN: wave = (mg = wv>>2 over token halves, ns = wv&3 over 48-ch slices).
// fc1: wave wv owns N-slice of 96 (acc1[4][6]); Hs = SB stride 776 (64 rows, 99.3 KB).
__global__ __launch_bounds__(512, 2) void ap_mlp_mfma(
    const f16* __restrict__ fb, const f16* __restrict__ apW,
    const float* __restrict__ apb,
    const float* __restrict__ n3w, const float* __restrict__ n3b,
    const f16* __restrict__ w1, const float* __restrict__ b1,
    const f16* __restrict__ w2, const float* __restrict__ b2,
    const float* __restrict__ n4w, const float* __restrict__ n4b,
    const f16* __restrict__ res, float* __restrict__ out) {
  const int tid = threadIdx.x;
  const int lane = tid & 63;
  const int wv = tid >> 6;             // 0..7
  const int l15 = lane & 15;
  const int quad = lane >> 4;
  const int wi = blockIdx.x;           // window index, 64 tokens
  const int wt0 = wi * 64;
  // overlay: As = SB stride 200 (ap + fc1, rows 0..63); Hs = SB stride 776 (fc2)
  __shared__ __align__(16) f16 SB[64 * 776];
  __shared__ float rs3[64], rq3[64], rs4[64], rq4[64];
  if (tid < 64) { rs3[tid] = 0.f; rq3[tid] = 0.f; rs4[tid] = 0.f; rq4[tid] = 0.f; }
  for (int i = tid; i < 64 * 24; i += 512) {
    const int r = i / 24, s = i - r * 24;
    *(half8*)(SB + r * 200 + s * 8) = *(const half8*)(fb + (size_t)(wt0 + r) * 192 + s * 8);
  }

  // ---- phase A setup ----
  const int mg = wv >> 2;              // token half: rows mg*32..mg*32+31
  const int ns = wv & 3;               // 48-channel slice
  const int mrow = mg * 32;
  int cc[3]; float apbv[3], w3v[3], b3v[3];
  #pragma unroll
  for (int j = 0; j < 3; ++j) {
    cc[j] = ns * 48 + j * 16 + l15;
    apbv[j] = apb[cc[j]]; w3v[j] = n3w[cc[j]]; b3v[j] = n3b[cc[j]];
  }
  half8 wp[6][3];
  #pragma unroll
  for (int u6 = 0; u6 < 6; ++u6) {
    const int k = u6 * 32 + quad * 8;
    #pragma unroll
    for (int j = 0; j < 3; ++j)
      wp[u6][j] = *(const half8*)(apW + (size_t)cc[j] * 192 + k);
  }
  // fc1 N-slice (96 per wave) bias prefetch
  const int nb1 = wv * 96;
  float b1v[6];
  #pragma unroll
  for (int j = 0; j < 6; ++j) b1v[j] = b1[nb1 + j * 16 + l15];
  __syncthreads();

  // ---- phase A: attn-proj GEMM (M=64, N=192, K=192) + LN3 ----
  f32x4 accp[2][3];
  #pragma unroll
  for (int mt = 0; mt < 2; ++mt)
    #pragma unroll
    for (int j = 0; j < 3; ++j) accp[mt][j] = (f32x4)0.f;
  #pragma unroll
  for (int u6 = 0; u6 < 6; ++u6) {
    const int k = u6 * 32 + quad * 8;
    const half8 a0 = *(const half8*)(SB + (mrow + l15) * 200 + k);
    const half8 a1 = *(const half8*)(SB + (mrow + 16 + l15) * 200 + k);
    #pragma unroll
    for (int j = 0; j < 3; ++j) {
      accp[0][j] = mfma16(a0, wp[u6][j], accp[0][j]);
      accp[1][j] = mfma16(a1, wp[u6][j], accp[1][j]);
    }
  }
  #pragma unroll
  for (int mt = 0; mt < 2; ++mt)
    #pragma unroll
    for (int j = 0; j < 3; ++j)
      #pragma unroll
      for (int reg = 0; reg < 4; ++reg) accp[mt][j][reg] += apbv[j];

  { // LN3 reduce: 4 ns-waves contribute 48 channels each per row
    float ssum[8], ssq[8];
    #pragma unroll
    for (int mt = 0; mt < 2; ++mt)
      #pragma unroll
      for (int reg = 0; reg < 4; ++reg) {
        const int i = mt * 4 + reg;
        const float a0 = accp[mt][0][reg], a1 = accp[mt][1][reg], a2 = accp[mt][2][reg];
        ssum[i] = a0 + a1 + a2;
        ssq[i] = a0 * a0 + a1 * a1 + a2 * a2;
      }
    #pragma unroll
    for (int mm = 1; mm < 16; mm <<= 1)
      #pragma unroll
      for (int i = 0; i < 8; ++i) {
        ssum[i] += __shfl_xor(ssum[i], mm, 64);
        ssq[i] += __shfl_xor(ssq[i], mm, 64);
      }
    if (l15 == 0) {
      #pragma unroll
      for (int mt = 0; mt < 2; ++mt)
        #pragma unroll
        for (int reg = 0; reg < 4; ++reg) {
          const int row = mrow + mt * 16 + quad * 4 + reg;
          atomicAdd(&rs3[row], ssum[mt * 4 + reg]);
          atomicAdd(&rq3[row], ssq[mt * 4 + reg]);
        }
    }
  }
  __syncthreads();
  // normalize + write m into As (f16, same rounding as before)
  #pragma unroll
  for (int mt = 0; mt < 2; ++mt)
    #pragma unroll
    for (int reg = 0; reg < 4; ++reg) {
      const int row = mrow + mt * 16 + quad * 4 + reg;
      const float mean = rs3[row] * (1.f / 192.f);
      const float rstd = rsqrtf(rq3[row] * (1.f / 192.f) - mean * mean + 1e-5f);
      #pragma unroll
      for (int j = 0; j < 3; ++j)
        SB[row * 200 + cc[j]] = (f16)((accp[mt][j][reg] - mean) * rstd * w3v[j] + b3v[j]);
    }
  __syncthreads();

  // ---- phase B: fc1 (M=64, N=768, K=192); wave owns N-slice 96 = 6 tiles ----
  f32x4 acc1[4][6];
  #pragma unroll
  for (int mt = 0; mt < 4; ++mt)
    #pragma unroll
    for (int j = 0; j < 6; ++j) acc1[mt][j] = (f32x4)0.f;
  for (int kc = 0; kc < 6; ++kc) {
    const int k = kc * 32 + quad * 8;
    half8 wb[6];
    #pragma unroll
    for (int j = 0; j < 6; ++j)
      wb[j] = *(const half8*)(w1 + (size_t)(nb1 + j * 16 + l15) * 192 + k);
    half8 a[4];
    #pragma unroll
    for (int mt = 0; mt < 4; ++mt)
      a[mt] = *(const half8*)(SB + (mt * 16 + l15) * 200 + k);
    #pragma unroll
    for (int j = 0; j < 6; ++j)
      #pragma unroll
      for (int mt = 0; mt < 4; ++mt) acc1[mt][j] = mfma16(a[mt], wb[j], acc1[mt][j]);
  }
  __syncthreads();   // all As reads complete before Hs overwrites SB
  #pragma unroll
  for (int j = 0; j < 6; ++j) {
    const int n = nb1 + j * 16 + l15;
    #pragma unroll
    for (int mt = 0; mt < 4; ++mt)
      #pragma unroll
      for (int reg = 0; reg < 4; ++reg) {
        const int row = mt * 16 + quad * 4 + reg;
        SB[row * 776 + n] = (f16)gelu(acc1[mt][j][reg] + b1v[j]);
      }
  }
  __syncthreads();

  // prefetch residual into registers (hides HBM latency under fc2)
  const int b_img = wi >> 8;
  const int wy = (wi >> 4) & 15;
  const int wx = wi & 15;
  float rr[2][3][4];
  #pragma unroll
  for (int mt = 0; mt < 2; ++mt) {
    const int t0 = mrow + mt * 16 + quad * 4;
    const int y = wy * 8 + (t0 >> 3);
    const int xx0 = wx * 8 + (t0 & 7);
    const size_t tokbase = ((size_t)(b_img * 128 + y)) * 128 + xx0;
    #pragma unroll
    for (int j = 0; j < 3; ++j)
      #pragma unroll
      for (int reg = 0; reg < 4; ++reg)
        rr[mt][j][reg] = (float)res[(tokbase + reg) * 192 + cc[j]];
  }

  // ---- phase C: fc2 (M=64, N=192, K=768); wave = (mg, ns) ----
  f32x4 acc2[2][3];
  #pragma unroll
  for (int mt = 0; mt < 2; ++mt)
    #pragma unroll
    for (int j = 0; j < 3; ++j) acc2[mt][j] = (f32x4)0.f;
  for (int g = 0; g < 6; ++g) {      // 6 groups x 4 kc, 12 batched loads each
    half8 wb[4][3];
    #pragma unroll
    for (int u = 0; u < 4; ++u) {
      const int k = (g * 4 + u) * 32 + quad * 8;
      #pragma unroll
      for (int j = 0; j < 3; ++j)
        wb[u][j] = *(const half8*)(w2 + (size_t)cc[j] * 768 + k);
    }
    #pragma unroll
    for (int u = 0; u < 4; ++u) {
      const int k = (g * 4 + u) * 32 + quad * 8;
      const half8 a0 = *(const half8*)(SB + (mrow + l15) * 776 + k);
      const half8 a1 = *(const half8*)(SB + (mrow + 16 + l15) * 776 + k);
      #pragma unroll
      for (int j = 0; j < 3; ++j) {
        acc2[0][j] = mfma16(a0, wb[u][j], acc2[0][j]);
        acc2[1][j] = mfma16(a1, wb[u][j], acc2[1][j]);
      }
    }
  }
  float w4[3], b4[3];
  #pragma unroll
  for (int j = 0; j < 3; ++j) {
    const float bj = b2[cc[j]];
    w4[j] = n4w[cc[j]]; b4[j] = n4b[cc[j]];
    #pragma unroll
    for (int mt = 0; mt < 2; ++mt)
      #pragma unroll
      for (int reg = 0; reg < 4; ++reg)
        acc2[mt][j][reg] = 2.f * (acc2[mt][j][reg] + bj);   // m = m + m
  }
  float ssum[8], ssq[8];
  #pragma unroll
  for (int mt = 0; mt < 2; ++mt)
    #pragma unroll
    for (int reg = 0; reg < 4; ++reg) {
      const int i = mt * 4 + reg;
      const float a0 = acc2[mt][0][reg], a1 = acc2[mt][1][reg], a2 = acc2[mt][2][reg];
      ssum[i] = a0 + a1 + a2;
      ssq[i] = a0 * a0 + a1 * a1 + a2 * a2;
    }
  #pragma unroll
  for (int mm = 1; mm < 16; mm <<= 1)
    #pragma unroll
    for (int i = 0; i < 8; ++i) {
      ssum[i] += __shfl_xor(ssum[i], mm, 64);
      ssq[i] += __shfl_xor(ssq[i], mm, 64);
    }
  if (l15 == 0) {
    #pragma unroll
    for (int mt = 0; mt < 2; ++mt)
      #pragma unroll
      for (int reg = 0; reg < 4; ++reg) {
        const int row = mrow + mt * 16 + quad * 4 + reg;
        atomicAdd(&rs4[row], ssum[mt * 4 + reg]);
        atomicAdd(&rq4[row], ssq[mt * 4 + reg]);
      }
  }
  __syncthreads();

  #pragma unroll
  for (int mt = 0; mt < 2; ++mt) {
    const int t0 = mrow + mt * 16 + quad * 4;
    const int y = wy * 8 + (t0 >> 3);
    const int x0 = wx * 8 + (t0 & 7);
    float mean[4], rstd[4];
    #pragma unroll
    for (int reg = 0; reg < 4; ++reg) {
      const int row = t0 + reg;
      mean[reg] = rs4[row] * (1.f / 192.f);
      rstd[reg] = rsqrtf(rq4[row] * (1.f / 192.f) - mean[reg] * mean[reg] + 1e-5f);
    }
    #pragma unroll
    for (int j = 0; j < 3; ++j) {
      float4 o;
      float vals[4];
      #pragma unroll
      for (int reg = 0; reg < 4; ++reg)
        vals[reg] = (acc2[mt][j][reg] - mean[reg]) * rstd[reg] * w4[j] + b4[j] + rr[mt][j][reg];
      o.x = vals[0]; o.y = vals[1]; o.z = vals[2]; o.w = vals[3];
      float* dst = out + ((size_t)(b_img * 192 + cc[j])) * 16384 + (y * 128 + x0);
      *(float4*)dst = o;
    }
  }
}

extern "C" void kernel_launch(void* const* d_in, const int* in_sizes, int n_in,
                              void* d_out, int out_size, void* d_ws, size_t ws_size,
                              hipStream_t stream) {
  (void)in_sizes; (void)n_in; (void)out_size;
  const float* x    = (const float*)d_in[0];
  const float* v    = (const float*)d_in[1];
  const float* pq_w = (const float*)d_in[2];
  const float* pq_b = (const float*)d_in[3];
  const float* pv_w = (const float*)d_in[4];
  const float* pv_b = (const float*)d_in[5];
  const float* n1w  = (const float*)d_in[6];
  const float* n1b  = (const float*)d_in[7];
  const float* n2w  = (const float*)d_in[8];
  const float* n2b  = (const float*)d_in[9];
  const float* n3w  = (const float*)d_in[10];
  const float* n3b  = (const float*)d_in[11];
  const float* n4w  = (const float*)d_in[12];
  const float* n4b  = (const float*)d_in[13];
  const float* qW   = (const float*)d_in[14];
  const float* kvW  = (const float*)d_in[15];
  const float* apW  = (const float*)d_in[16];
  const float* apb  = (const float*)d_in[17];
  const float* rpb  = (const float*)d_in[18];
  const float* w1   = (const float*)d_in[19];
  const float* b1   = (const float*)d_in[20];
  const float* w2   = (const float*)d_in[21];
  const float* b2   = (const float*)d_in[22];
  float* out = (float*)d_out;

  const size_t HE = 25165824;           // elements per half-slot (tokens*192)
  f16* xp   = (f16*)d_ws;               // conv(x) -> res (in-place in ln_qkv)
  f16* vp   = xp + HE;                  // conv(v) -> fb (attn out)
  f16* vvb  = vp + HE;                  // Wr -> v projection -> apW/w1/w2 f16
  f16* qb   = (f16*)d_out;              // q (scratch in d_out)
  f16* kb   = qb + HE;                  // k (scratch in d_out)
  f16* fb   = vp;                       // alias: vp dead after ln_qkv
  f16* Wr   = vvb;                      // 2*192*864 f16, dead before ln_qkv writes vvb
  f16* wtail = vvb + HE;                // qW/kvW f16 (110592 elems) if room
  const bool big = ws_size >= (3 * HE + 110592) * sizeof(f16);

  reorder_w<<<big ? 1728 : 1296, 256, 0, stream>>>(pq_w, pv_w, qW, kvW, Wr,
                                                   big ? wtail : (f16*)nullptr);
  conv3x3_mfma<<<2048, 256, 0, stream>>>(x, v, Wr, pq_b, pv_b, xp, vp);
  if (big)
    ln_qkv_mfma<true><<<4096, 256, 0, stream>>>(xp, vp, n1w, n1b, n2w, n2b,
                                                wtail, wtail + 36864, qb, kb, vvb);
  else
    ln_qkv_mfma<false><<<4096, 256, 0, stream>>>(xp, vp, n1w, n1b, n2w, n2b,
                                                 qW, kvW, qb, kb, vvb);
  attn64<<<16384, 64, 0, stream>>>(qb, kb, vvb, rpb, fb);
  reorder_w2<<<1296, 256, 0, stream>>>(apW, w1, w2, vvb);   // vvb dead after attn64
  ap_mlp_mfma<<<2048, 512, 0, stream>>>(fb, vvb, apb, n3w, n3b,
                                        vvb + 36864, b1, vvb + 184320, b2,
                                        n4w, n4b, xp, out);
}

// Round 9
// 1030.506 us; speedup vs baseline: 1.0823x; 1.0823x over previous
//
#include <hip/hip_runtime.h>
#include <hip/hip_bf16.h>
#include <math.h>

typedef _Float16 f16;
typedef _Float16 half8 __attribute__((ext_vector_type(8)));
typedef float f32x4 __attribute__((ext_vector_type(4)));

#define IMG 128
#define CIN 96
#define CH  192
#define SCALE_Q 0.2041241452319315f   // 24^-0.5

__device__ __forceinline__ f32x4 mfma16(half8 a, half8 b, f32x4 c) {
  return __builtin_amdgcn_mfma_f32_16x16x32_f16(a, b, c, 0, 0, 0);
}

// weight fragment loader: WH=true -> pre-converted f16 row-major [N][K];
// WH=false -> fp32 row-major with per-element RTE cvt (bit-exact legacy path)
template <bool WH>
__device__ __forceinline__ half8 loadW(const void* W, int row, int k, int ldk) {
  if constexpr (WH) {
    return *(const half8*)((const f16*)W + (size_t)row * ldk + k);
  } else {
    const float* p = (const float*)W + (size_t)row * ldk + k;
    const float4 a = *(const float4*)p;
    const float4 b = *(const float4*)(p + 4);
    half8 h;
    h[0] = (f16)a.x; h[1] = (f16)a.y; h[2] = (f16)a.z; h[3] = (f16)a.w;
    h[4] = (f16)b.x; h[5] = (f16)b.y; h[6] = (f16)b.z; h[7] = (f16)b.w;
    return h;
  }
}

// exact-GELU via Abramowitz-Stegun erf approx (|err| <= 1.5e-7)
// rcp via v_rcp_f32 (~1 ulp) instead of full div: error far below f16 noise
__device__ __forceinline__ float gelu(float x) {
  const float u = 0.70710678118654752f * x;
  const float a = fabsf(u);
  const float t = __builtin_amdgcn_rcpf(1.0f + 0.3275911f * a);
  const float poly = t * (0.254829592f + t * (-0.284496736f +
                     t * (1.421413741f + t * (-1.453152027f + t * 1.061405429f))));
  float er = 1.0f - poly * __expf(-u * u);
  er = (u < 0.f) ? -er : er;
  return 0.5f * x * (1.0f + er);
}

// ---------- kernel 0: conv weights OIHW fp32 -> [co][(ky*3+kx)*96+ci] f16;
//                      optionally qW/kvW fp32 -> f16 straight copy into wq16 ----------
__global__ __launch_bounds__(256) void reorder_w(
    const float* __restrict__ pq_w, const float* __restrict__ pv_w,
    const float* __restrict__ qW, const float* __restrict__ kvW,
    f16* __restrict__ Wr, f16* __restrict__ wq16) {
  const int i = blockIdx.x * 256 + threadIdx.x;
  if (i < 2 * 192 * 864) {
    const int which = i / (192 * 864);
    const int rem = i - which * (192 * 864);
    const int co = rem / 864;
    const int kk = rem - co * 864;
    const int s = kk / 96;           // ky*3+kx
    const int ci = kk - s * 96;
    const float* src = which ? pv_w : pq_w;
    Wr[i] = (f16)src[co * 864 + ci * 9 + s];
  } else if (wq16) {
    const int j = i - 2 * 192 * 864;       // 0..110591: qW(36864) then kvW(73728)
    if (j < 110592)
      wq16[j] = (f16)(j < 36864 ? qW[j] : kvW[j - 36864]);
  }
}

// ---------- kernel 0b (after attn64): apW,w1,w2 fp32 -> f16 into dead v buffer ----------
__global__ __launch_bounds__(256) void reorder_w2(
    const float* __restrict__ apW, const float* __restrict__ w1,
    const float* __restrict__ w2, f16* __restrict__ dst) {
  const int i = blockIdx.x * 256 + threadIdx.x;
  if (i >= 331776) return;                 // 36864 + 147456 + 147456
  float v;
  if (i < 36864)       v = apW[i];
  else if (i < 184320) v = w1[i - 36864];
  else                 v = w2[i - 184320];
  dst[i] = (f16)v;
}

// ---------- kernel 1: implicit-GEMM MFMA 3x3 conv, 2 output rows per block ----------
// grid 2048 = {which(2)} x {b(8)} x {ypair(64)} x {xseg(2)}; block 256 (4 waves)
// M = 128 pixels (2 rows x 64), N = 192, K = 9*96   [round-5 proven form]
__global__ __launch_bounds__(256, 2) void conv3x3_mfma(
    const float* __restrict__ xin, const float* __restrict__ vin,
    const f16* __restrict__ Wr,
    const float* __restrict__ pq_b, const float* __restrict__ pv_b,
    f16* __restrict__ xp, f16* __restrict__ vp) {
  int bz = blockIdx.x;
  const int which = bz >> 10; bz &= 1023;
  const int b = bz >> 7;
  const int yp = (bz >> 1) & 63;
  const int xseg = bz & 1;
  const int y0 = yp * 2;
  const int x0 = xseg * 64;
  const float* in = which ? vin : xin;
  const float* bias = which ? pv_b : pq_b;
  const f16* W = Wr + (size_t)which * 192 * 864;
  f16* out = which ? vp : xp;

  // im2col halo tile: [r(4)][x(66)][c(96)], pixel stride 104
  // reused after MFMA as output staging [tok(128)][ch(192)] stride 204
  __shared__ __align__(16) f16 ST[4 * 66 * 104];
  const int tid = threadIdx.x;
  // batched branchless staging: 99 elements/thread = 9 batches x 11
  #pragma unroll
  for (int batch = 0; batch < 9; ++batch) {
    float vals[11];
    bool oks[11];
    int sts[11];
    #pragma unroll
    for (int u = 0; u < 11; ++u) {
      const int i = tid + (batch * 11 + u) * 256;
      const int r = i / 6336;                 // 6336 = 96*66
      const int rem2 = i - r * 6336;
      const int c = rem2 / 66;
      const int xx = rem2 - c * 66;
      const int gy = y0 + r - 1;
      const int gx = x0 - 1 + xx;
      oks[u] = ((unsigned)gy < IMG) && ((unsigned)gx < IMG);
      const int cgy = min(max(gy, 0), IMG - 1);
      const int cgx = min(max(gx, 0), IMG - 1);
      vals[u] = in[(((size_t)b * CIN + c) * IMG + cgy) * IMG + cgx];
      sts[u] = (r * 66 + xx) * 104 + c;
    }
    #pragma unroll
    for (int u = 0; u < 11; ++u)
      ST[sts[u]] = oks[u] ? (f16)vals[u] : (f16)0.f;
  }
  __syncthreads();

  const int lane = tid & 63;
  const int wv = tid >> 6;
  const int l15 = lane & 15;
  const int quad = lane >> 4;
  const int nb = wv * 48;          // N-slice 48 per wave

  f32x4 acc[8][3];
  #pragma unroll
  for (int mt = 0; mt < 8; ++mt)
    #pragma unroll
    for (int j = 0; j < 3; ++j) acc[mt][j] = (f32x4)0.f;

  #pragma unroll
  for (int s = 0; s < 9; ++s) {
    const int ky = s / 3, kx = s - ky * 3;
    #pragma unroll
    for (int kstep = 0; kstep < 3; ++kstep) {
      const int k = kstep * 32 + quad * 8;   // ci offset
      half8 a[8];
      #pragma unroll
      for (int mt = 0; mt < 8; ++mt)
        a[mt] = *(const half8*)(ST + (((mt >> 2) + ky) * 66 + (mt & 3) * 16 + l15 + kx) * 104 + k);
      #pragma unroll
      for (int j = 0; j < 3; ++j) {
        const half8 bf = *(const half8*)(W + (size_t)(nb + j * 16 + l15) * 864 + s * 96 + k);
        #pragma unroll
        for (int mt = 0; mt < 8; ++mt) acc[mt][j] = mfma16(a[mt], bf, acc[mt][j]);
      }
    }
  }
  __syncthreads();   // all ST reads done; reuse as output staging

  // transpose through LDS: [lt(128)][ch(192)] stride 204
  #pragma unroll
  for (int j = 0; j < 3; ++j) {
    const int n = nb + j * 16 + l15;
    const float bn = bias[n];
    #pragma unroll
    for (int mt = 0; mt < 8; ++mt) {
      const int lt = (mt >> 2) * 64 + (mt & 3) * 16 + quad * 4;
      #pragma unroll
      for (int reg = 0; reg < 4; ++reg)
        ST[(lt + reg) * 204 + n] = (f16)(acc[mt][j][reg] + bn);
    }
  }
  __syncthreads();

  // contiguous half8 stores: 128 tok x 24 chunks = 3072 / 256 threads = 12 each
  const size_t rowbase0 = ((size_t)(b * IMG + y0) * IMG + x0) * CH;
  const size_t rowbase1 = ((size_t)(b * IMG + y0 + 1) * IMG + x0) * CH;
  #pragma unroll
  for (int it = 0; it < 12; ++it) {
    const int i = tid + it * 256;
    const int tok = i / 24, c8 = i - tok * 24;
    const half8 hval = *(const half8*)(ST + tok * 204 + c8 * 8);
    const int trow = tok >> 6, tx = tok & 63;
    f16* dst = out + (trow ? rowbase1 : rowbase0) + (size_t)tx * CH + c8 * 8;
    *(half8*)dst = hval;
  }
}

// ---------- kernel 2: LN1/LN2 + q/k/v projection (MFMA) + res=x+v in-place ----------
// block 256 (4 waves), Mtile = 32 tokens, N = 576 (q|k|v), K = 192
template <bool WH>
__global__ __launch_bounds__(256, 1) void ln_qkv_mfma(
    f16* __restrict__ xp, const f16* __restrict__ vp,
    const float* __restrict__ n1w, const float* __restrict__ n1b,
    const float* __restrict__ n2w, const float* __restrict__ n2b,
    const void* __restrict__ qW, const void* __restrict__ kvW,
    f16* __restrict__ qb, f16* __restrict__ kb, f16* __restrict__ vb) {
  const int tid = threadIdx.x;
  const int lane = tid & 63;
  const int wv = tid >> 6;
  const int l15 = lane & 15;
  const int quad = lane >> 4;
  const int tok0 = blockIdx.x * 32;
  // union: Ax (stride 200, 6400) + Av (6400) during MFMA; Os (32x588) after
  __shared__ __align__(16) f16 U[32 * 588];
  f16* Ax = U;
  f16* Av = U + 6400;

  { // stage + LN (8 threads per token, 24 elements each)
    const int r = tid >> 3;
    const int s = tid & 7;
    const size_t gbase = (size_t)(tok0 + r) * 192 + s * 24;
    half8 hx[3], hv[3];
    const half8* px = (const half8*)(xp + gbase);
    const half8* pv = (const half8*)(vp + gbase);
    #pragma unroll
    for (int i = 0; i < 3; ++i) { hx[i] = px[i]; hv[i] = pv[i]; }
    float xv[24], vvv[24];
    float sx = 0.f, sx2 = 0.f, sv = 0.f, sv2 = 0.f;
    #pragma unroll
    for (int i = 0; i < 24; ++i) {
      xv[i] = (float)hx[i >> 3][i & 7];
      vvv[i] = (float)hv[i >> 3][i & 7];
      sx += xv[i]; sx2 += xv[i] * xv[i];
      sv += vvv[i]; sv2 += vvv[i] * vvv[i];
    }
    half8 hr[3];
    #pragma unroll
    for (int i = 0; i < 24; ++i) hr[i >> 3][i & 7] = (f16)(xv[i] + vvv[i]);
    half8* pr = (half8*)(xp + gbase);
    #pragma unroll
    for (int i = 0; i < 3; ++i) pr[i] = hr[i];   // residual, in-place
    #pragma unroll
    for (int m = 1; m < 8; m <<= 1) {
      sx += __shfl_xor(sx, m, 64); sx2 += __shfl_xor(sx2, m, 64);
      sv += __shfl_xor(sv, m, 64); sv2 += __shfl_xor(sv2, m, 64);
    }
    const float mx = sx * (1.f / 192.f);
    const float rx = rsqrtf(sx2 * (1.f / 192.f) - mx * mx + 1e-5f);
    const float mv = sv * (1.f / 192.f);
    const float rv = rsqrtf(sv2 * (1.f / 192.f) - mv * mv + 1e-5f);
    #pragma unroll
    for (int i = 0; i < 24; ++i) {
      const int c = s * 24 + i;
      Ax[r * 200 + c] = (f16)((xv[i] - mx) * rx * n1w[c] + n1b[c]);
      Av[r * 200 + c] = (f16)((vvv[i] - mv) * rv * n2w[c] + n2b[c]);
    }
  }
  __syncthreads();

  const int nb = wv * 144;
  f32x4 acc[2][9];
  #pragma unroll
  for (int mt = 0; mt < 2; ++mt)
    #pragma unroll
    for (int j = 0; j < 9; ++j) acc[mt][j] = (f32x4)0.f;

  for (int kc = 0; kc < 6; ++kc) {
    const int k = kc * 32 + quad * 8;
    half8 wb[9];
    #pragma unroll
    for (int j = 0; j < 9; ++j) {
      const int n0 = nb + j * 16;
      if (n0 < 192) wb[j] = loadW<WH>(qW, n0 + l15, k, 192);
      else          wb[j] = loadW<WH>(kvW, n0 - 192 + l15, k, 192);
    }
    const half8 ax0 = *(const half8*)(Ax + l15 * 200 + k);
    const half8 ax1 = *(const half8*)(Ax + (16 + l15) * 200 + k);
    const half8 av0 = *(const half8*)(Av + l15 * 200 + k);
    const half8 av1 = *(const half8*)(Av + (16 + l15) * 200 + k);
    #pragma unroll
    for (int j = 0; j < 9; ++j) {
      const int n0 = nb + j * 16;
      if (n0 < 192) {
        acc[0][j] = mfma16(ax0, wb[j], acc[0][j]);
        acc[1][j] = mfma16(ax1, wb[j], acc[1][j]);
      } else {
        acc[0][j] = mfma16(av0, wb[j], acc[0][j]);
        acc[1][j] = mfma16(av1, wb[j], acc[1][j]);
      }
    }
  }
  __syncthreads();   // Ax/Av reads done; reuse U as output staging

  // stage acc into Os[r(32)][n(576)] stride 588 (f16 conversion identical to before)
  #pragma unroll
  for (int j = 0; j < 9; ++j) {
    const int n = nb + j * 16 + l15;
    const float scale = (n < 192) ? SCALE_Q : 1.f;
    #pragma unroll
    for (int mt = 0; mt < 2; ++mt)
      #pragma unroll
      for (int reg = 0; reg < 4; ++reg) {
        const int r = mt * 16 + quad * 4 + reg;
        U[r * 588 + n] = (f16)(acc[mt][j][reg] * scale);
      }
  }
  __syncthreads();

  // copy out: 3 bufs x 4 windows x 8 heads x (8 tok x 3 chunks) = 2304 half8
  // all 32 tokens share one image row y; x = x0b + r
  const int yrow = (tok0 >> 7) & 127;
  const int bb = tok0 >> 14;
  const int x0b = tok0 & 127;
  const int wib = bb * 256 + ((yrow >> 3) << 4) + (x0b >> 3);  // window of r=0
  const int trow = (yrow & 7) * 8;
  f16* const bufs[3] = {qb, kb, vb};
  #pragma unroll
  for (int it = 0; it < 9; ++it) {
    const int i = tid + it * 256;
    const int c24 = i % 24;            // t8*3 + c3
    const int g = i / 24;              // buf*32 + wloc*8 + h
    const int h = g & 7;
    const int g2 = g >> 3;             // buf*4 + wloc
    const int wloc = g2 & 3;
    const int buf = g2 >> 2;
    const int t8 = c24 / 3, c3 = c24 - t8 * 3;
    const int r = wloc * 8 + t8;
    const half8 hval = *(const half8*)(U + r * 588 + buf * 192 + h * 24 + c3 * 8);
    f16* dst = bufs[buf] + (size_t)(wib + wloc) * 12288 + (trow + t8) * 24 + h * 1536 + c3 * 8;
    *(half8*)dst = hval;
  }
}

// ---------- kernel 3: windowed attention, one block (1 wave) per (window, head) ----------
// [round-5 proven form — scalar staging is conflict-free; half8 variant regressed]
__global__ __launch_bounds__(64) void attn64(
    const f16* __restrict__ qb, const f16* __restrict__ kb,
    const f16* __restrict__ vb, const float* __restrict__ rpb,
    f16* __restrict__ fb) {
  const int wh = blockIdx.x;           // w*8 + h
  const int h = wh & 7;
  const int w = wh >> 3;
  const int t = threadIdx.x;
  __shared__ __align__(16) float ks[64 * 24];
  __shared__ __align__(16) float vs[64 * 24];
  __shared__ float bsh[225];
  const f16* kbase = kb + (size_t)wh * 1536;
  const f16* vbase = vb + (size_t)wh * 1536;
  for (int i = t; i < 1536; i += 64) { ks[i] = (float)kbase[i]; vs[i] = (float)vbase[i]; }
  for (int i = t; i < 225; i += 64) bsh[i] = rpb[i * 8 + h];
  float q[24];
  const f16* qrow = qb + ((size_t)wh * 64 + t) * 24;
  #pragma unroll
  for (int d = 0; d < 24; ++d) q[d] = (float)qrow[d];
  __syncthreads();
  const int qy = t >> 3, qx = t & 7;
  float s[64];
  float mx = -1e30f;
  #pragma unroll
  for (int kk = 0; kk < 64; ++kk) {
    float acc = 0.f;
    #pragma unroll
    for (int d = 0; d < 24; ++d) acc += q[d] * ks[kk * 24 + d];
    const int ky = kk >> 3, kx = kk & 7;
    acc += bsh[(qy - ky + 7) * 15 + (qx - kx + 7)];
    s[kk] = acc;
    mx = fmaxf(mx, acc);
  }
  float sum = 0.f;
  #pragma unroll
  for (int kk = 0; kk < 64; ++kk) { const float e = __expf(s[kk] - mx); s[kk] = e; sum += e; }
  const float inv = 1.0f / sum;
  float o[24];
  #pragma unroll
  for (int d = 0; d < 24; ++d) o[d] = 0.f;
  #pragma unroll
  for (int kk = 0; kk < 64; ++kk) {
    const float p = s[kk];
    #pragma unroll
    for (int d = 0; d < 24; ++d) o[d] += p * vs[kk * 24 + d];
  }
  f16* orow = fb + ((size_t)w * 64 + t) * 192 + h * 24;
  #pragma unroll
  for (int d = 0; d < 24; ++d) orow[d] = (f16)(o[d] * inv);
}

// ---------- kernel 4: attn-proj + LN3 + fc1 + GELU + fc2 + x2 + LN4 + residual + NCHW ----------
// M=32, 256 threads, split-H: H materialized in two 384-wide halves (Hh 32x392, 25KB)
// so LDS = 38.4 KB -> 3 blocks/CU (12 waves) at (256,3); fc1 regs halved (acc1[2][6]).
// fc2 accumulates across both K-halves; math order identical to fused version.
__global__ __launch_bounds__(256, 3) void ap_mlp_mfma(
    const f16* __restrict__ fb, const f16* __restrict__ apW,
    const float* __restrict__ apb,
    const float* __restrict__ n3w, const float* __restrict__ n3b,
    const f16* __restrict__ w1, const float* __restrict__ b1,
    const f16* __restrict__ w2, const float* __restrict__ b2,
    const float* __restrict__ n4w, const float* __restrict__ n4b,
    const f16* __restrict__ res, float* __restrict__ out) {
  const int tid = threadIdx.x;
  const int lane = tid & 63;
  const int wv = tid >> 6;
  const int l15 = lane & 15;
  const int quad = lane >> 4;
  const int wt0 = blockIdx.x * 32;
  __shared__ __align__(16) f16 As[32 * 200];   // attn-out -> m (LN3'd), K=192
  __shared__ __align__(16) f16 Hh[32 * 392];   // one 384-wide half of H
  __shared__ float rs3[32], rq3[32], rs4[32], rq4[32];
  if (tid < 32) { rs3[tid] = 0.f; rq3[tid] = 0.f; rs4[tid] = 0.f; rq4[tid] = 0.f; }
  for (int i = tid; i < 32 * 24; i += 256) {
    const int r = i / 24, s = i - r * 24;
    *(half8*)(As + r * 200 + s * 8) = *(const half8*)(fb + (size_t)(wt0 + r) * 192 + s * 8);
  }

  // ---- setup: ap weights batched, biases for both fc1 halves ----
  const int nbp = wv * 48;
  int cc[3]; float apbv[3], w3v[3], b3v[3];
  #pragma unroll
  for (int j = 0; j < 3; ++j) {
    cc[j] = nbp + j * 16 + l15;
    apbv[j] = apb[cc[j]]; w3v[j] = n3w[cc[j]]; b3v[j] = n3b[cc[j]];
  }
  half8 wp[6][3];
  #pragma unroll
  for (int u6 = 0; u6 < 6; ++u6) {
    const int k = u6 * 32 + quad * 8;
    #pragma unroll
    for (int j = 0; j < 3; ++j)
      wp[u6][j] = *(const half8*)(apW + (size_t)cc[j] * 192 + k);
  }
  const int nh = wv * 96;              // fc1 per-wave N-base within a 384-half
  float b1vA[6], b1vB[6];
  #pragma unroll
  for (int j = 0; j < 6; ++j) {
    b1vA[j] = b1[nh + j * 16 + l15];
    b1vB[j] = b1[384 + nh + j * 16 + l15];
  }
  __syncthreads();

  // ---- phase A: attn-proj GEMM (M=32, N=192, K=192) + LN3 ----
  f32x4 accp[2][3];
  #pragma unroll
  for (int mt = 0; mt < 2; ++mt)
    #pragma unroll
    for (int j = 0; j < 3; ++j) accp[mt][j] = (f32x4)0.f;
  #pragma unroll
  for (int u6 = 0; u6 < 6; ++u6) {
    const int k = u6 * 32 + quad * 8;
    const half8 a0 = *(const half8*)(As + l15 * 200 + k);
    const half8 a1 = *(const half8*)(As + (16 + l15) * 200 + k);
    #pragma unroll
    for (int j = 0; j < 3; ++j) {
      accp[0][j] = mfma16(a0, wp[u6][j], accp[0][j]);
      accp[1][j] = mfma16(a1, wp[u6][j], accp[1][j]);
    }
  }
  #pragma unroll
  for (int mt = 0; mt < 2; ++mt)
    #pragma unroll
    for (int j = 0; j < 3; ++j)
      #pragma unroll
      for (int reg = 0; reg < 4; ++reg) accp[mt][j][reg] += apbv[j];

  { // LN3 reduce
    float ssum[8], ssq[8];
    #pragma unroll
    for (int mt = 0; mt < 2; ++mt)
      #pragma unroll
      for (int reg = 0; reg < 4; ++reg) {
        const int i = mt * 4 + reg;
        const float a0 = accp[mt][0][reg], a1 = accp[mt][1][reg], a2 = accp[mt][2][reg];
        ssum[i] = a0 + a1 + a2;
        ssq[i] = a0 * a0 + a1 * a1 + a2 * a2;
      }
    #pragma unroll
    for (int mm = 1; mm < 16; mm <<= 1)
      #pragma unroll
      for (int i = 0; i < 8; ++i) {
        ssum[i] += __shfl_xor(ssum[i], mm, 64);
        ssq[i] += __shfl_xor(ssq[i], mm, 64);
      }
    if (l15 == 0) {
      #pragma unroll
      for (int mt = 0; mt < 2; ++mt)
        #pragma unroll
        for (int reg = 0; reg < 4; ++reg) {
          const int row = mt * 16 + quad * 4 + reg;
          atomicAdd(&rs3[row], ssum[mt * 4 + reg]);
          atomicAdd(&rq3[row], ssq[mt * 4 + reg]);
        }
    }
  }
  __syncthreads();   // atomics visible + all As reads done
  // normalize + write m into As (same rounding as before)
  #pragma unroll
  for (int mt = 0; mt < 2; ++mt)
    #pragma unroll
    for (int reg = 0; reg < 4; ++reg) {
      const int row = mt * 16 + quad * 4 + reg;
      const float mean = rs3[row] * (1.f / 192.f);
      const float rstd = rsqrtf(rq3[row] * (1.f / 192.f) - mean * mean + 1e-5f);
      #pragma unroll
      for (int j = 0; j < 3; ++j)
        As[row * 200 + cc[j]] = (f16)((accp[mt][j][reg] - mean) * rstd * w3v[j] + b3v[j]);
    }
  __syncthreads();

  // ---- fc1 half-1: N = 0..383 (wave slice 96), K=192 ----
  f32x4 acc1[2][6];
  #pragma unroll
  for (int mt = 0; mt < 2; ++mt)
    #pragma unroll
    for (int j = 0; j < 6; ++j) acc1[mt][j] = (f32x4)0.f;
  for (int kc = 0; kc < 6; ++kc) {
    const int k = kc * 32 + quad * 8;
    half8 wb[6];
    #pragma unroll
    for (int j = 0; j < 6; ++j)
      wb[j] = *(const half8*)(w1 + (size_t)(nh + j * 16 + l15) * 192 + k);
    const half8 a0 = *(const half8*)(As + l15 * 200 + k);
    const half8 a1 = *(const half8*)(As + (16 + l15) * 200 + k);
    #pragma unroll
    for (int j = 0; j < 6; ++j) {
      acc1[0][j] = mfma16(a0, wb[j], acc1[0][j]);
      acc1[1][j] = mfma16(a1, wb[j], acc1[1][j]);
    }
  }
  #pragma unroll
  for (int j = 0; j < 6; ++j) {
    const int n = nh + j * 16 + l15;
    #pragma unroll
    for (int mt = 0; mt < 2; ++mt)
      #pragma unroll
      for (int reg = 0; reg < 4; ++reg) {
        const int row = mt * 16 + quad * 4 + reg;
        Hh[row * 392 + n] = (f16)gelu(acc1[mt][j][reg] + b1vA[j]);
      }
  }
  __syncthreads();   // Hh half-1 visible

  // ---- fc2 part-1: k = 0..383 over Hh ----
  f32x4 acc2[2][3];
  #pragma unroll
  for (int mt = 0; mt < 2; ++mt)
    #pragma unroll
    for (int j = 0; j < 3; ++j) acc2[mt][j] = (f32x4)0.f;
  for (int g = 0; g < 3; ++g) {
    half8 wb2[4][3];
    #pragma unroll
    for (int u = 0; u < 4; ++u) {
      const int k = (g * 4 + u) * 32 + quad * 8;
      #pragma unroll
      for (int j = 0; j < 3; ++j)
        wb2[u][j] = *(const half8*)(w2 + (size_t)cc[j] * 768 + k);
    }
    #pragma unroll
    for (int u = 0; u < 4; ++u) {
      const int k = (g * 4 + u) * 32 + quad * 8;
      const half8 a0 = *(const half8*)(Hh + l15 * 392 + k);
      const half8 a1 = *(const half8*)(Hh + (16 + l15) * 392 + k);
      #pragma unroll
      for (int j = 0; j < 3; ++j) {
        acc2[0][j] = mfma16(a0, wb2[u][j], acc2[0][j]);
        acc2[1][j] = mfma16(a1, wb2[u][j], acc2[1][j]);
      }
    }
  }

  // ---- fc1 half-2 MFMA (reads As only — overlaps before Hh-overwrite barrier) ----
  #pragma unroll
  for (int mt = 0; mt < 2; ++mt)
    #pragma unroll
    for (int j = 0; j < 6; ++j) acc1[mt][j] = (f32x4)0.f;
  for (int kc = 0; kc < 6; ++kc) {
    const int k = kc * 32 + quad * 8;
    half8 wb[6];
    #pragma unroll
    for (int j = 0; j < 6; ++j)
      wb[j] = *(const half8*)(w1 + (size_t)(384 + nh + j * 16 + l15) * 192 + k);
    const half8 a0 = *(const half8*)(As + l15 * 200 + k);
    const half8 a1 = *(const half8*)(As + (16 + l15) * 200 + k);
    #pragma unroll
    for (int j = 0; j < 6; ++j) {
      acc1[0][j] = mfma16(a0, wb[j], acc1[0][j]);
      acc1[1][j] = mfma16(a1, wb[j], acc1[1][j]);
    }
  }
  __syncthreads();   // all fc2 part-1 Hh reads done
  #pragma unroll
  for (int j = 0; j < 6; ++j) {
    const int n = nh + j * 16 + l15;
    #pragma unroll
    for (int mt = 0; mt < 2; ++mt)
      #pragma unroll
      for (int reg = 0; reg < 4; ++reg) {
        const int row = mt * 16 + quad * 4 + reg;
        Hh[row * 392 + n] = (f16)gelu(acc1[mt][j][reg] + b1vB[j]);
      }
  }
  __syncthreads();   // Hh half-2 visible

  // prefetch residual (hides under fc2 part-2)
  const int wi = wt0 >> 6;
  const int t_base = wt0 & 63;
  const int b_img = wi >> 8;
  const int wy = (wi >> 4) & 15;
  const int wx = wi & 15;
  float rr[2][3][4];
  #pragma unroll
  for (int mt = 0; mt < 2; ++mt) {
    const int t0 = t_base + mt * 16 + quad * 4;
    const int y = wy * 8 + (t0 >> 3);
    const int xx0 = wx * 8 + (t0 & 7);
    const size_t tokbase = ((size_t)(b_img * 128 + y)) * 128 + xx0;
    #pragma unroll
    for (int j = 0; j < 3; ++j)
      #pragma unroll
      for (int reg = 0; reg < 4; ++reg)
        rr[mt][j][reg] = (float)res[(tokbase + reg) * 192 + cc[j]];
  }

  // ---- fc2 part-2: k = 384..767 over Hh ----
  for (int g = 3; g < 6; ++g) {
    half8 wb2[4][3];
    #pragma unroll
    for (int u = 0; u < 4; ++u) {
      const int k = (g * 4 + u) * 32 + quad * 8;
      #pragma unroll
      for (int j = 0; j < 3; ++j)
        wb2[u][j] = *(const half8*)(w2 + (size_t)cc[j] * 768 + k);
    }
    #pragma unroll
    for (int u = 0; u < 4; ++u) {
      const int kl = (g * 4 + u) * 32 + quad * 8 - 384;
      const half8 a0 = *(const half8*)(Hh + l15 * 392 + kl);
      const half8 a1 = *(const half8*)(Hh + (16 + l15) * 392 + kl);
      #pragma unroll
      for (int j = 0; j < 3; ++j) {
        acc2[0][j] = mfma16(a0, wb2[u][j], acc2[0][j]);
        acc2[1][j] = mfma16(a1, wb2[u][j], acc2[1][j]);
      }
    }
  }
  float w4[3], b4[3];
  #pragma unroll
  for (int j = 0; j < 3; ++j) {
    const float bj = b2[cc[j]];
    w4[j] = n4w[cc[j]]; b4[j] = n4b[cc[j]];
    #pragma unroll
    for (int mt = 0; mt < 2; ++mt)
      #pragma unroll
      for (int reg = 0; reg < 4; ++reg)
        acc2[mt][j][reg] = 2.f * (acc2[mt][j][reg] + bj);   // m = m + m
  }
  float ssum[8], ssq[8];
  #pragma unroll
  for (int mt = 0; mt < 2; ++mt)
    #pragma unroll
    for (int reg = 0; reg < 4; ++reg) {
      const int i = mt * 4 + reg;
      const float a0 = acc2[mt][0][reg], a1 = acc2[mt][1][reg], a2 = acc2[mt][2][reg];
      ssum[i] = a0 + a1 + a2;
      ssq[i] = a0 * a0 + a1 * a1 + a2 * a2;
    }
  #pragma unroll
  for (int mm = 1; mm < 16; mm <<= 1)
    #pragma unroll
    for (int i = 0; i < 8; ++i) {
      ssum[i] += __shfl_xor(ssum[i], mm, 64);
      ssq[i] += __shfl_xor(ssq[i], mm, 64);
    }
  if (l15 == 0) {
    #pragma unroll
    for (int mt = 0; mt < 2; ++mt)
      #pragma unroll
      for (int reg = 0; reg < 4; ++reg) {
        const int row = mt * 16 + quad * 4 + reg;
        atomicAdd(&rs4[row], ssum[mt * 4 + reg]);
        atomicAdd(&rq4[row], ssq[mt * 4 + reg]);
      }
  }
  __syncthreads();

  #pragma unroll
  for (int mt = 0; mt < 2; ++mt) {
    const int row0 = mt * 16 + quad * 4;
    const int t0 = t_base + row0;
    const int y = wy * 8 + (t0 >> 3);
    const int x0 = wx * 8 + (t0 & 7);
    float mean[4], rstd[4];
    #pragma unroll
    for (int reg = 0; reg < 4; ++reg) {
      const int row = row0 + reg;
      mean[reg] = rs4[row] * (1.f / 192.f);
      rstd[reg] = rsqrtf(rq4[row] * (1.f / 192.f) - mean[reg] * mean[reg] + 1e-5f);
    }
    #pragma unroll
    for (int j = 0; j < 3; ++j) {
      float4 o;
      float vals[4];
      #pragma unroll
      for (int reg = 0; reg < 4; ++reg)
        vals[reg] = (acc2[mt][j][reg] - mean[reg]) * rstd[reg] * w4[j] + b4[j] + rr[mt][j][reg];
      o.x = vals[0]; o.y = vals[1]; o.z = vals[2]; o.w = vals[3];
      float* dst = out + ((size_t)(b_img * 192 + cc[j])) * 16384 + (y * 128 + x0);
      *(float4*)dst = o;
    }
  }
}

extern "C" void kernel_launch(void* const* d_in, const int* in_sizes, int n_in,
                              void* d_out, int out_size, void* d_ws, size_t ws_size,
                              hipStream_t stream) {
  (void)in_sizes; (void)n_in; (void)out_size;
  const float* x    = (const float*)d_in[0];
  const float* v    = (const float*)d_in[1];
  const float* pq_w = (const float*)d_in[2];
  const float* pq_b = (const float*)d_in[3];
  const float* pv_w = (const float*)d_in[4];
  const float* pv_b = (const float*)d_in[5];
  const float* n1w  = (const float*)d_in[6];
  const float* n1b  = (const float*)d_in[7];
  const float* n2w  = (const float*)d_in[8];
  const float* n2b  = (const float*)d_in[9];
  const float* n3w  = (const float*)d_in[10];
  const float* n3b  = (const float*)d_in[11];
  const float* n4w  = (const float*)d_in[12];
  const float* n4b  = (const float*)d_in[13];
  const float* qW   = (const float*)d_in[14];
  const float* kvW  = (const float*)d_in[15];
  const float* apW  = (const float*)d_in[16];
  const float* apb  = (const float*)d_in[17];
  const float* rpb  = (const float*)d_in[18];
  const float* w1   = (const float*)d_in[19];
  const float* b1   = (const float*)d_in[20];
  const float* w2   = (const float*)d_in[21];
  const float* b2   = (const float*)d_in[22];
  float* out = (float*)d_out;

  const size_t HE = 25165824;           // elements per half-slot (tokens*192)
  f16* xp   = (f16*)d_ws;               // conv(x) -> res (in-place in ln_qkv)
  f16* vp   = xp + HE;                  // conv(v) -> fb (attn out)
  f16* vvb  = vp + HE;                  // Wr -> v projection -> apW/w1/w2 f16
  f16* qb   = (f16*)d_out;              // q (scratch in d_out)
  f16* kb   = qb + HE;                  // k (scratch in d_out)
  f16* fb   = vp;                       // alias: vp dead after ln_qkv
  f16* Wr   = vvb;                      // 2*192*864 f16, dead before ln_qkv writes vvb
  f16* wtail = vvb + HE;                // qW/kvW f16 (110592 elems) if room
  const bool big = ws_size >= (3 * HE + 110592) * sizeof(f16);

  reorder_w<<<big ? 1728 : 1296, 256, 0, stream>>>(pq_w, pv_w, qW, kvW, Wr,
                                                   big ? wtail : (f16*)nullptr);
  conv3x3_mfma<<<2048, 256, 0, stream>>>(x, v, Wr, pq_b, pv_b, xp, vp);
  if (big)
    ln_qkv_mfma<true><<<4096, 256, 0, stream>>>(xp, vp, n1w, n1b, n2w, n2b,
                                                wtail, wtail + 36864, qb, kb, vvb);
  else
    ln_qkv_mfma<false><<<4096, 256, 0, stream>>>(xp, vp, n1w, n1b, n2w, n2b,
                                                 qW, kvW, qb, kb, vvb);
  attn64<<<16384, 64, 0, stream>>>(qb, kb, vvb, rpb, fb);
  reorder_w2<<<1296, 256, 0, stream>>>(apW, w1, w2, vvb);   // vvb dead after attn64
  ap_mlp_mfma<<<4096, 256, 0, stream>>>(fb, vvb, apb, n3w, n3b,
                                        vvb + 36864, b1, vvb + 184320, b2,
                                        n4w, n4b, xp, out);
}